// Round 4
// baseline (776.435 us; speedup 1.0000x reference)
//
#include <hip/hip_runtime.h>

// Shift op: x (288,256,256) f32 -> out (288*9,256,256) f32
// out[c*9 + dy*3 + dx, y, x] = x[c, y+dy-1, x+dx-1]  (zero-padded)

constexpr int C = 288;
constexpr int H = 256;
constexpr int W = 256;
constexpr int W4 = W / 4;                       // 64 float4 vectors per row
constexpr unsigned TOTAL_VEC = (unsigned)C * 9u * (unsigned)H * (unsigned)W4; // 42,467,328

__device__ __forceinline__ float ld_or_zero(const float* __restrict__ row, int sx) {
    return ((unsigned)sx < (unsigned)W) ? row[sx] : 0.0f;
}

__global__ __launch_bounds__(256) void shift_kernel(const float* __restrict__ x,
                                                    float4* __restrict__ out) {
    unsigned stride = gridDim.x * blockDim.x;
    for (unsigned i = blockIdx.x * blockDim.x + threadIdx.x; i < TOTAL_VEC; i += stride) {
        // Decompose i -> (co, y, xv): i = ((co*H) + y)*W4 + xv
        unsigned xv = i & (W4 - 1);             // vector index within row
        unsigned r  = i >> 6;                   // / W4
        unsigned y  = r & (H - 1);
        unsigned co = r >> 8;                   // / H
        unsigned c  = co / 9u;                  // magic-mul
        unsigned s  = co - c * 9u;
        int dy = (int)(s / 3u);
        int dx = (int)(s - (unsigned)dy * 3u);

        int sy = (int)y + dy - 1;
        float4 v;
        if ((unsigned)sy < (unsigned)H) {
            const float* __restrict__ row = x + ((size_t)c * H + (unsigned)sy) * W;
            int sx0 = (int)(xv * 4u) + dx - 1;
            if (sx0 >= 0 && sx0 + 3 < W) {
                // fully interior (the common case): 4 coalesced dword loads
                v.x = row[sx0];
                v.y = row[sx0 + 1];
                v.z = row[sx0 + 2];
                v.w = row[sx0 + 3];
            } else {
                v.x = ld_or_zero(row, sx0);
                v.y = ld_or_zero(row, sx0 + 1);
                v.z = ld_or_zero(row, sx0 + 2);
                v.w = ld_or_zero(row, sx0 + 3);
            }
        } else {
            v = make_float4(0.f, 0.f, 0.f, 0.f);
        }
        out[i] = v;
    }
}

extern "C" void kernel_launch(void* const* d_in, const int* in_sizes, int n_in,
                              void* d_out, int out_size, void* d_ws, size_t ws_size,
                              hipStream_t stream) {
    const float* x = (const float*)d_in[0];
    float4* out = (float4*)d_out;
    // Memory-bound streaming: cap grid, grid-stride the rest (G11).
    // 2048 blocks x 256 thr = 524288 threads; ~81 float4 stores each.
    dim3 grid(2048), block(256);
    shift_kernel<<<grid, block, 0, stream>>>(x, out);
}